// Round 1
// baseline (1224.868 us; speedup 1.0000x reference)
//
#include <hip/hip_runtime.h>
#include <math.h>

// ---- problem constants (fixed shapes) ----
#define NPTS 16384
#define DIM  512
#define KSEL 11            // K+1: keep 11 smallest incl. self, drop min at the end
#define NSPLIT 4
#define COLS_PER_SPLIT (NPTS / NSPLIT)   // 4096
#define BM 256             // rows per block (8 waves x 32 rows)
#define BN 32              // columns staged per iteration (32 KB LDS)
#define ROWBYTES 1024      // DIM * 2 bytes (bf16), one point's row

typedef __attribute__((ext_vector_type(4))) float f32x4;
typedef __attribute__((ext_vector_type(8))) short s16x8;

// round-to-nearest-even fp32 -> bf16 bits
__device__ __forceinline__ unsigned short f2bf(float f) {
    unsigned int x = __float_as_uint(f);
    return (unsigned short)((x + 0x7FFFu + ((x >> 16) & 1u)) >> 16);
}

__device__ __forceinline__ void gload_lds16(const void* g, void* l) {
    __builtin_amdgcn_global_load_lds(
        (const __attribute__((address_space(1))) void*)g,
        (__attribute__((address_space(3))) void*)l, 16, 0, 0);
}

// ---- kernel 1: fp32 -> bf16, XOR-swizzled layout: byte = row*1024 + ((k*2) ^ ((row&7)<<4))
__global__ void prep_convert(const float* __restrict__ obs, char* __restrict__ obsb) {
    const int t   = blockIdx.x * 256 + threadIdx.x;   // one 16B block each
    const int row = t >> 6;
    const int kb  = t & 63;                           // 16B block within the row
    const float4* s = (const float4*)(obs + (unsigned long)row * DIM + kb * 8);
    const float4 a = s[0], b = s[1];
    uint4 o;
    o.x = (unsigned int)f2bf(a.x) | ((unsigned int)f2bf(a.y) << 16);
    o.y = (unsigned int)f2bf(a.z) | ((unsigned int)f2bf(a.w) << 16);
    o.z = (unsigned int)f2bf(b.x) | ((unsigned int)f2bf(b.y) << 16);
    o.w = (unsigned int)f2bf(b.z) | ((unsigned int)f2bf(b.w) << 16);
    *(uint4*)(obsb + (unsigned long)row * ROWBYTES + ((kb * 16) ^ ((row & 7) << 4))) = o;
}

// ---- kernel 2: sq[i] = sum_k obs[i][k]^2 (fp32, one wave per row)
__global__ void prep_sq(const float* __restrict__ obs, float* __restrict__ sq) {
    const int wv = threadIdx.x >> 6, ln = threadIdx.x & 63;
    const int row = blockIdx.x * 4 + wv;
    const float4* p = (const float4*)(obs + (unsigned long)row * DIM + ln * 8);
    const float4 a = p[0], b = p[1];
    float s = a.x*a.x + a.y*a.y + a.z*a.z + a.w*a.w
            + b.x*b.x + b.y*b.y + b.z*b.z + b.w*b.w;
    #pragma unroll
    for (int o = 32; o; o >>= 1) s += __shfl_xor(s, o);
    if (ln == 0) sq[row] = s;
}

// ---- kernel 3: fused distance GEMM + per-row top-11-smallest (per column split)
__global__ __launch_bounds__(512, 2) void knn_main(
    const char* __restrict__ obsb, const float* __restrict__ sq,
    float* __restrict__ cand)
{
    __shared__ char  Bsh[BN * ROWBYTES];     // 32 KB, swizzled same as global
    __shared__ float heap[BM][KSEL];
    __shared__ float thr[BM];
    __shared__ int   maxi[BM];

    const int tid = threadIdx.x;
    const int wv = tid >> 6, ln = tid & 63;
    const int sp = blockIdx.x >> 6;          // column split 0..3
    const int rt = blockIdx.x & 63;          // row tile 0..63
    const int R0 = rt * BM;
    const int C0 = sp * COLS_PER_SPLIT;
    const int wrow0 = R0 + wv * 32;          // this wave's 32 rows (2 strips of 16)

    for (int i = tid; i < BM * KSEL; i += 512) (&heap[0][0])[i] = __builtin_inff();
    for (int i = tid; i < BM; i += 512) { thr[i] = __builtin_inff(); maxi[i] = 0; }

    // A fragments in registers: lane ln holds rows wrow0+s*16+(ln&15), k-slice (ln>>4)*8
    s16x8 afrag[2][16];
    #pragma unroll
    for (int s = 0; s < 2; ++s) {
        const int row = wrow0 + s * 16 + (ln & 15);
        const unsigned long rb = (unsigned long)row * ROWBYTES;
        const int kx = (((ln >> 4) << 4)) ^ ((row & 7) << 4);
        #pragma unroll
        for (int t = 0; t < 16; ++t)
            afrag[s][t] = *(const s16x8*)(obsb + rb + ((t * 64) ^ kx));
    }
    float sqr[2][4];
    #pragma unroll
    for (int s = 0; s < 2; ++s)
        #pragma unroll
        for (int j = 0; j < 4; ++j)
            sqr[s][j] = sq[wrow0 + s * 16 + ((ln >> 4) << 2) + j];

    for (int c0 = C0; c0 < C0 + COLS_PER_SPLIT; c0 += BN) {
        __syncthreads();   // protect Bsh from previous iteration's readers
        {   // stage 32 cols x 1KB, linear copy (swizzle baked into global layout)
            const char* gsrc = obsb + (unsigned long)c0 * ROWBYTES + wv * 1024 + ln * 16;
            char* ldst = Bsh + wv * 1024;    // wave-uniform LDS base
            #pragma unroll
            for (int r = 0; r < 4; ++r)
                gload_lds16(gsrc + r * 8192, ldst + r * 8192);
        }
        __syncthreads();

        const float sqc[2] = { sq[c0 + (ln & 15)], sq[c0 + 16 + (ln & 15)] };

        #pragma unroll
        for (int sub = 0; sub < 2; ++sub) {
            const int colL = sub * 16 + (ln & 15);
            const char* bbase = Bsh + colL * ROWBYTES;
            const int kx = (((ln >> 4) << 4)) ^ ((colL & 7) << 4);
            f32x4 acc0 = {0.f, 0.f, 0.f, 0.f};
            f32x4 acc1 = {0.f, 0.f, 0.f, 0.f};
            #pragma unroll
            for (int t = 0; t < 16; ++t) {
                const s16x8 b = *(const s16x8*)(bbase + ((t * 64) ^ kx));
                acc0 = __builtin_amdgcn_mfma_f32_16x16x32_bf16(afrag[0][t], b, acc0, 0, 0, 0);
                acc1 = __builtin_amdgcn_mfma_f32_16x16x32_bf16(afrag[1][t], b, acc1, 0, 0, 0);
            }
            // epilogue: d2 = sq[r] + sq[c] - 2*dot ; maintain per-row top-11 smallest
            #pragma unroll
            for (int s = 0; s < 2; ++s) {
                const f32x4 acc = s ? acc1 : acc0;
                #pragma unroll
                for (int j = 0; j < 4; ++j) {
                    const float v = sqr[s][j] + sqc[sub] - 2.0f * acc[j];
                    const int rl = wv * 32 + s * 16 + ((ln >> 4) << 2) + j;
                    unsigned long long m = __ballot(v < thr[rl]);
                    while (m) {
                        const int src = __builtin_ctzll(m);
                        m &= m - 1;
                        const float vv = __shfl(v, src);
                        const int rr = wv * 32 + s * 16 + ((src >> 4) << 2) + j;
                        if (ln == 0 && vv < thr[rr]) {
                            heap[rr][maxi[rr]] = vv;
                            float mx = heap[rr][0]; int mq = 0;
                            #pragma unroll
                            for (int p = 1; p < KSEL; ++p) {
                                const float h = heap[rr][p];
                                if (h > mx) { mx = h; mq = p; }
                            }
                            thr[rr] = mx; maxi[rr] = mq;
                        }
                    }
                }
            }
        }
    }
    __syncthreads();
    for (int i = tid; i < BM * KSEL; i += 512) {
        const int rl = i / KSEL, q = i - rl * KSEL;
        cand[(unsigned long)(R0 + rl) * (NSPLIT * KSEL) + sp * KSEL + q] = heap[rl][q];
    }
}

// ---- kernel 4: merge 4x11 split candidates per row -> exact top-11 -> output
__global__ void merge_out(const float* __restrict__ cand, float* __restrict__ out) {
    const int row = blockIdx.x * 256 + threadIdx.x;
    const float* c = cand + (unsigned long)row * (NSPLIT * KSEL);
    float arr[KSEL];
    #pragma unroll
    for (int q = 0; q < KSEL; ++q) arr[q] = c[q];
    float mx = arr[0]; int mi = 0;
    #pragma unroll
    for (int q = 1; q < KSEL; ++q) if (arr[q] > mx) { mx = arr[q]; mi = q; }
    for (int i = KSEL; i < NSPLIT * KSEL; ++i) {
        const float v = c[i];
        if (v < mx) {
            #pragma unroll
            for (int q = 0; q < KSEL; ++q) if (q == mi) arr[q] = v;
            mx = arr[0]; mi = 0;
            #pragma unroll
            for (int q = 1; q < KSEL; ++q) if (arr[q] > mx) { mx = arr[q]; mi = q; }
        }
    }
    float mn = arr[0];
    #pragma unroll
    for (int q = 1; q < KSEL; ++q) mn = fminf(mn, arr[q]);
    float ssum = 0.f;
    #pragma unroll
    for (int q = 0; q < KSEL; ++q) ssum += sqrtf(fmaxf(arr[q], 0.f));
    out[row] = log1pf((ssum - sqrtf(fmaxf(mn, 0.f))) * 0.1f);
}

extern "C" void kernel_launch(void* const* d_in, const int* in_sizes, int n_in,
                              void* d_out, int out_size, void* d_ws, size_t ws_size,
                              hipStream_t stream) {
    const float* obs = (const float*)d_in[0];
    float* out = (float*)d_out;
    char* ws = (char*)d_ws;

    char*  obsb = ws;                                        // 16 MB swizzled bf16
    float* sq   = (float*)(ws + (size_t)NPTS * ROWBYTES);    // 64 KB
    float* cand = (float*)(ws + (size_t)NPTS * ROWBYTES + NPTS * sizeof(float)); // ~2.75 MB

    prep_convert<<<NPTS * 64 / 256, 256, 0, stream>>>(obs, obsb);
    prep_sq<<<NPTS / 4, 256, 0, stream>>>(obs, sq);
    knn_main<<<64 * NSPLIT, 512, 0, stream>>>(obsb, sq, cand);
    merge_out<<<NPTS / 256, 256, 0, stream>>>(cand, out);
}

// Round 2
// 571.665 us; speedup vs baseline: 2.1426x; 2.1426x over previous
//
#include <hip/hip_runtime.h>
#include <math.h>

// ---- problem constants (fixed shapes) ----
#define NPTS 16384
#define DIM  512
#define KSEL 11                   // K+1 smallest incl. self; min dropped at the end
#define NSPLIT 4
#define CPS   (NPTS / NSPLIT)     // 4096 columns per split
#define BM    128                 // rows per block (4 waves x 32 rows)
#define BN    32                  // columns staged per iteration (32 KB)
#define ITERS (CPS / BN)          // 128
#define ROWBYTES 1024             // DIM * 2 bytes (bf16)

typedef __attribute__((ext_vector_type(4))) float f32x4;
typedef __attribute__((ext_vector_type(8))) short s16x8;

__device__ __forceinline__ unsigned short f2bf(float f) {
    unsigned int x = __float_as_uint(f);
    return (unsigned short)((x + 0x7FFFu + ((x >> 16) & 1u)) >> 16);
}

__device__ __forceinline__ void gload_lds16(const void* g, void* l) {
    __builtin_amdgcn_global_load_lds(
        (const __attribute__((address_space(1))) void*)g,
        (__attribute__((address_space(3))) void*)l, 16, 0, 0);
}
__device__ __forceinline__ void gload_lds4(const void* g, void* l) {
    __builtin_amdgcn_global_load_lds(
        (const __attribute__((address_space(1))) void*)g,
        (__attribute__((address_space(3))) void*)l, 4, 0, 0);
}

// scalar exact top-KSEL (smallest) scan over v[0..n); result in a[KSEL]; returns 11th smallest
__device__ __forceinline__ float topk_scan(const float* v, int n, float* a) {
    #pragma unroll
    for (int p = 0; p < KSEL; ++p) a[p] = v[p];
    float mx = a[0];
    #pragma unroll
    for (int p = 1; p < KSEL; ++p) mx = fmaxf(mx, a[p]);
    for (int i = KSEL; i < n; ++i) {
        const float x = v[i];
        if (x < mx) {
            bool done = false;
            #pragma unroll
            for (int p = 0; p < KSEL; ++p) {
                const bool rep = (!done) && (a[p] == mx);
                a[p] = rep ? x : a[p];
                done = done || rep;
            }
            mx = a[0];
            #pragma unroll
            for (int p = 1; p < KSEL; ++p) mx = fmaxf(mx, a[p]);
        }
    }
    return mx;
}

// ---- kernel 1: fp32 -> bf16, XOR-swizzled: byte = row*1024 + ((kb*16) ^ ((row&7)<<4))
__global__ void prep_convert(const float* __restrict__ obs, char* __restrict__ obsb) {
    const int t   = blockIdx.x * 256 + threadIdx.x;
    const int row = t >> 6;
    const int kb  = t & 63;
    const float4* s = (const float4*)(obs + (unsigned long)row * DIM + kb * 8);
    const float4 a = s[0], b = s[1];
    uint4 o;
    o.x = (unsigned int)f2bf(a.x) | ((unsigned int)f2bf(a.y) << 16);
    o.y = (unsigned int)f2bf(a.z) | ((unsigned int)f2bf(a.w) << 16);
    o.z = (unsigned int)f2bf(b.x) | ((unsigned int)f2bf(b.y) << 16);
    o.w = (unsigned int)f2bf(b.z) | ((unsigned int)f2bf(b.w) << 16);
    *(uint4*)(obsb + (unsigned long)row * ROWBYTES + ((kb * 16) ^ ((row & 7) << 4))) = o;
}

// ---- kernel 2: sq[i] = ||x_i||^2 in fp32
__global__ void prep_sq(const float* __restrict__ obs, float* __restrict__ sq) {
    const int wv = threadIdx.x >> 6, ln = threadIdx.x & 63;
    const int row = blockIdx.x * 4 + wv;
    const float4* p = (const float4*)(obs + (unsigned long)row * DIM + ln * 8);
    const float4 a = p[0], b = p[1];
    float s = a.x*a.x + a.y*a.y + a.z*a.z + a.w*a.w
            + b.x*b.x + b.y*b.y + b.z*b.z + b.w*b.w;
    #pragma unroll
    for (int o = 32; o; o >>= 1) s += __shfl_xor(s, o);
    if (ln == 0) sq[row] = s;
}

// ---- kernel 3: two-phase fused distance GEMM + exact per-row top-11
__global__ __launch_bounds__(256, 2) void knn_main(
    const char* __restrict__ obsb, const float* __restrict__ sq,
    float* __restrict__ cand)
{
    __shared__ __align__(16) char Braw[2][BN * ROWBYTES];   // 64 KB double buffer
    __shared__ float sqs[2][BN];
    __shared__ float Trow[BM];

    const int tid = threadIdx.x;
    const int wv = tid >> 6, ln = tid & 63;
    const int sp = blockIdx.x >> 7;          // split 0..3
    const int rt = blockIdx.x & 127;         // row tile 0..127
    const int R0 = rt * BM;
    const int C0 = sp * CPS;
    const int wrow0 = R0 + wv * 32;
    const int lr = ln & 15;                  // row within strip
    const int kc = ln >> 4;                  // k-chunk 0..3

    // A fragments (row points), registers, used by both phases
    s16x8 afrag[2][16];
    float sqr[2];
    #pragma unroll
    for (int s = 0; s < 2; ++s) {
        const int row = wrow0 + s * 16 + lr;
        const unsigned long rb = (unsigned long)row * ROWBYTES;
        const int kxA = (kc << 4) ^ ((row & 7) << 4);
        #pragma unroll
        for (int t = 0; t < 16; ++t)
            afrag[s][t] = *(const s16x8*)(obsb + rb + ((t * 64) ^ kxA));
        sqr[s] = sq[row];
    }

    // LDS read bases for column frags: addr = bse[cg][t&1] + (t>>1)*128
    int bse[2][2];
    #pragma unroll
    for (int cg = 0; cg < 2; ++cg) {
        const int colL = cg * 16 + lr;
        const int s7 = (colL & 7) << 4;
        const int kxlow = (kc << 4) ^ (s7 & 0x30);
        const int b6 = (s7 >> 6) & 1;
        bse[cg][0] = colL * ROWBYTES + kxlow + (b6 << 6);
        bse[cg][1] = colL * ROWBYTES + kxlow + ((1 ^ b6) << 6);
    }

#define STAGE(BUF, CITER) do {                                                  \
        const char* gs_ = obsb + (unsigned long)(C0 + (CITER) * BN) * ROWBYTES  \
                          + wv * 1024 + ln * 16;                                \
        char* lb_ = &Braw[BUF][0] + wv * 1024;                                  \
        _Pragma("unroll")                                                       \
        for (int r_ = 0; r_ < 8; ++r_)                                          \
            gload_lds16(gs_ + r_ * 4096, lb_ + r_ * 4096);                      \
        if (tid < BN)                                                           \
            gload_lds4(sq + C0 + (CITER) * BN + tid, &sqs[BUF][0]);             \
    } while (0)

#define GEMM_BODY(CUR)                                                          \
        const char* bp = &Braw[CUR][0];                                         \
        f32x4 acc[2][2] = {{{0.f,0.f,0.f,0.f},{0.f,0.f,0.f,0.f}},               \
                           {{0.f,0.f,0.f,0.f},{0.f,0.f,0.f,0.f}}};              \
        _Pragma("unroll")                                                       \
        for (int cg = 0; cg < 2; ++cg) {                                        \
            _Pragma("unroll")                                                   \
            for (int t = 0; t < 16; ++t) {                                      \
                const s16x8 b = *(const s16x8*)(bp + bse[cg][t & 1] + (t >> 1) * 128); \
                acc[0][cg] = __builtin_amdgcn_mfma_f32_16x16x32_bf16(b, afrag[0][t], acc[0][cg], 0, 0, 0); \
                acc[1][cg] = __builtin_amdgcn_mfma_f32_16x16x32_bf16(b, afrag[1][t], acc[1][cg], 0, 0, 0); \
            }                                                                   \
        }                                                                       \
        f32x4 sqv[2];                                                           \
        sqv[0] = *(const f32x4*)&sqs[CUR][kc * 4];                              \
        sqv[1] = *(const f32x4*)&sqs[CUR][16 + kc * 4];

#define DIST(S, CG, R) fmaf(-2.0f, acc[S][CG][R], sqr[S] + sqv[CG][R])

    // ================= phase A: chunk minima =================
    float segmin[2][8];
    #pragma unroll
    for (int s = 0; s < 2; ++s)
        #pragma unroll
        for (int q = 0; q < 8; ++q) segmin[s][q] = __builtin_inff();

    STAGE(0, 0);
    __syncthreads();
    #pragma unroll 2
    for (int it = 0; it < ITERS; ++it) {
        const int cur = it & 1;
        if (it + 1 < ITERS) STAGE(cur ^ 1, it + 1);
        GEMM_BODY(cur);
        #pragma unroll
        for (int s = 0; s < 2; ++s)
            #pragma unroll
            for (int cg = 0; cg < 2; ++cg)
                #pragma unroll
                for (int r = 0; r < 4; ++r)
                    segmin[s][cg * 4 + r] = fminf(segmin[s][cg * 4 + r], DIST(s, cg, r));
        __syncthreads();
    }

    // gather 32 chunk-minima per row -> T = 11th smallest (valid upper bound)
    float* mins = (float*)&Braw[0][0];               // [BM][32]
    #pragma unroll
    for (int s = 0; s < 2; ++s)
        #pragma unroll
        for (int q = 0; q < 8; ++q)
            mins[(wv * 32 + s * 16 + lr) * 32 + kc * 8 + q] = segmin[s][q];
    __syncthreads();
    if (tid < BM) {
        float a[KSEL];
        Trow[tid] = topk_scan(mins + tid * 32, 32, a);
    }
    __syncthreads();

    // ================= phase B: seeded per-lane register heaps =================
    float hp[2][KSEL], mxv[2], tseed[2];
    #pragma unroll
    for (int s = 0; s < 2; ++s) {
        #pragma unroll
        for (int p = 0; p < KSEL; ++p) hp[s][p] = __builtin_inff();
        tseed[s] = Trow[wv * 32 + s * 16 + lr] + 1e-3f;
        mxv[s] = tseed[s];
    }

#define INS(S, VV) do {                                                         \
        if (__any((VV) < mxv[S])) {                                             \
            const bool ins_ = (VV) < mxv[S];                                    \
            float m0_ = hp[S][0];                                               \
            _Pragma("unroll")                                                   \
            for (int p = 1; p < KSEL; ++p) m0_ = fmaxf(m0_, hp[S][p]);          \
            bool done_ = !ins_;                                                 \
            _Pragma("unroll")                                                   \
            for (int p = 0; p < KSEL; ++p) {                                    \
                const bool rep_ = (!done_) && (hp[S][p] == m0_);                \
                hp[S][p] = rep_ ? (VV) : hp[S][p];                              \
                done_ = done_ || rep_;                                          \
            }                                                                   \
            float m1_ = hp[S][0];                                               \
            _Pragma("unroll")                                                   \
            for (int p = 1; p < KSEL; ++p) m1_ = fmaxf(m1_, hp[S][p]);          \
            mxv[S] = fminf(tseed[S], m1_);                                      \
        }                                                                       \
    } while (0)

#define PHASEB_STRIP(S) do {                                                    \
        const float w0 = DIST(S,0,0), w1 = DIST(S,0,1), w2 = DIST(S,0,2), w3 = DIST(S,0,3); \
        const float w4 = DIST(S,1,0), w5 = DIST(S,1,1), w6 = DIST(S,1,2), w7 = DIST(S,1,3); \
        const float vm = fminf(fminf(fminf(w0,w1),fminf(w2,w3)),                \
                               fminf(fminf(w4,w5),fminf(w6,w7)));               \
        if (__any(vm < mxv[S])) {                                               \
            INS(S,w0); INS(S,w1); INS(S,w2); INS(S,w3);                         \
            INS(S,w4); INS(S,w5); INS(S,w6); INS(S,w7);                         \
        }                                                                       \
    } while (0)

    STAGE(0, 0);
    __syncthreads();
    #pragma unroll 2
    for (int it = 0; it < ITERS; ++it) {
        const int cur = it & 1;
        if (it + 1 < ITERS) STAGE(cur ^ 1, it + 1);
        GEMM_BODY(cur);
        PHASEB_STRIP(0);
        PHASEB_STRIP(1);
        __syncthreads();
    }

    // merge 4 lanes x 11 per row -> exact top-11 of this split
    float* sc2 = (float*)&Braw[0][0];                // [BM][44]
    #pragma unroll
    for (int s = 0; s < 2; ++s)
        #pragma unroll
        for (int p = 0; p < KSEL; ++p)
            sc2[(wv * 32 + s * 16 + lr) * 44 + kc * KSEL + p] = hp[s][p];
    __syncthreads();
    if (tid < BM) {
        float a[KSEL];
        topk_scan(sc2 + tid * 44, 44, a);
        #pragma unroll
        for (int p = 0; p < KSEL; ++p)
            cand[(unsigned long)(R0 + tid) * (NSPLIT * KSEL) + sp * KSEL + p] = a[p];
    }
}

// ---- kernel 4: merge 4x11 split candidates per row -> output
__global__ void merge_out(const float* __restrict__ cand, float* __restrict__ out) {
    const int row = blockIdx.x * 256 + threadIdx.x;
    const float* c = cand + (unsigned long)row * (NSPLIT * KSEL);
    float arr[KSEL];
    topk_scan(c, NSPLIT * KSEL, arr);
    float mn = arr[0];
    #pragma unroll
    for (int q = 1; q < KSEL; ++q) mn = fminf(mn, arr[q]);
    float ssum = 0.f;
    #pragma unroll
    for (int q = 0; q < KSEL; ++q) ssum += sqrtf(fmaxf(arr[q], 0.f));
    out[row] = log1pf((ssum - sqrtf(fmaxf(mn, 0.f))) * 0.1f);
}

extern "C" void kernel_launch(void* const* d_in, const int* in_sizes, int n_in,
                              void* d_out, int out_size, void* d_ws, size_t ws_size,
                              hipStream_t stream) {
    const float* obs = (const float*)d_in[0];
    float* out = (float*)d_out;
    char* ws = (char*)d_ws;

    char*  obsb = ws;                                        // 16 MB swizzled bf16
    float* sq   = (float*)(ws + (size_t)NPTS * ROWBYTES);    // 64 KB
    float* cand = (float*)(ws + (size_t)NPTS * ROWBYTES + NPTS * sizeof(float)); // ~2.9 MB

    prep_convert<<<NPTS * 64 / 256, 256, 0, stream>>>(obs, obsb);
    prep_sq<<<NPTS / 4, 256, 0, stream>>>(obs, sq);
    knn_main<<<(NPTS / BM) * NSPLIT, 256, 0, stream>>>(obsb, sq, cand);  // 512 blocks
    merge_out<<<NPTS / 256, 256, 0, stream>>>(cand, out);
}

// Round 3
// 508.907 us; speedup vs baseline: 2.4069x; 1.1233x over previous
//
#include <hip/hip_runtime.h>
#include <math.h>

// ---- problem constants (fixed shapes) ----
#define NPTS 16384
#define DIM  512
#define KSEL 11                   // K+1 smallest incl. self; min dropped at the end
#define NSPLIT 4
#define CPS   (NPTS / NSPLIT)     // 4096 columns per split
#define BM    128                 // rows per block (4 waves x 32 rows)
#define BN    32                  // columns staged per iteration (32 KB)
#define ITERS (CPS / BN)          // 128
#define SAMPLE_ITERS 64           // phase A: threshold from first 2048 cols of split
#define ROWBYTES 1024             // DIM * 2 bytes (bf16)

typedef __attribute__((ext_vector_type(4))) float f32x4;
typedef __attribute__((ext_vector_type(8))) short s16x8;

__device__ __forceinline__ unsigned short f2bf(float f) {
    unsigned int x = __float_as_uint(f);
    return (unsigned short)((x + 0x7FFFu + ((x >> 16) & 1u)) >> 16);
}

__device__ __forceinline__ void gload_lds16(const void* g, void* l) {
    __builtin_amdgcn_global_load_lds(
        (const __attribute__((address_space(1))) void*)g,
        (__attribute__((address_space(3))) void*)l, 16, 0, 0);
}

// pin a loaded fragment: value becomes opaque -> compiler cannot rematerialize
__device__ __forceinline__ void pinreg(s16x8& v) {
    asm volatile("" : "+v"(v));
}

// scalar exact top-KSEL (smallest) scan over v[0..n); result in a[KSEL]; returns 11th smallest
__device__ __forceinline__ float topk_scan(const float* v, int n, float* a) {
    #pragma unroll
    for (int p = 0; p < KSEL; ++p) a[p] = v[p];
    float mx = a[0];
    #pragma unroll
    for (int p = 1; p < KSEL; ++p) mx = fmaxf(mx, a[p]);
    for (int i = KSEL; i < n; ++i) {
        const float x = v[i];
        if (x < mx) {
            bool done = false;
            #pragma unroll
            for (int p = 0; p < KSEL; ++p) {
                const bool rep = (!done) && (a[p] == mx);
                a[p] = rep ? x : a[p];
                done = done || rep;
            }
            mx = a[0];
            #pragma unroll
            for (int p = 1; p < KSEL; ++p) mx = fmaxf(mx, a[p]);
        }
    }
    return mx;
}

// ---- kernel 1: fp32 -> bf16, XOR-swizzled: byte = row*1024 + ((kb*16) ^ ((row&7)<<4))
__global__ void prep_convert(const float* __restrict__ obs, char* __restrict__ obsb) {
    const int t   = blockIdx.x * 256 + threadIdx.x;
    const int row = t >> 6;
    const int kb  = t & 63;
    const float4* s = (const float4*)(obs + (unsigned long)row * DIM + kb * 8);
    const float4 a = s[0], b = s[1];
    uint4 o;
    o.x = (unsigned int)f2bf(a.x) | ((unsigned int)f2bf(a.y) << 16);
    o.y = (unsigned int)f2bf(a.z) | ((unsigned int)f2bf(a.w) << 16);
    o.z = (unsigned int)f2bf(b.x) | ((unsigned int)f2bf(b.y) << 16);
    o.w = (unsigned int)f2bf(b.z) | ((unsigned int)f2bf(b.w) << 16);
    *(uint4*)(obsb + (unsigned long)row * ROWBYTES + ((kb * 16) ^ ((row & 7) << 4))) = o;
}

// ---- kernel 2: sq[i] = ||x_i||^2 in fp32
__global__ void prep_sq(const float* __restrict__ obs, float* __restrict__ sq) {
    const int wv = threadIdx.x >> 6, ln = threadIdx.x & 63;
    const int row = blockIdx.x * 4 + wv;
    const float4* p = (const float4*)(obs + (unsigned long)row * DIM + ln * 8);
    const float4 a = p[0], b = p[1];
    float s = a.x*a.x + a.y*a.y + a.z*a.z + a.w*a.w
            + b.x*b.x + b.y*b.y + b.z*b.z + b.w*b.w;
    #pragma unroll
    for (int o = 32; o; o >>= 1) s += __shfl_xor(s, o);
    if (ln == 0) sq[row] = s;
}

// ---- kernel 3: two-phase fused distance GEMM + exact per-row top-11
__global__ __launch_bounds__(256, 2) void knn_main(
    const char* __restrict__ obsb, const float* __restrict__ sq,
    float* __restrict__ cand)
{
    __shared__ __align__(16) char Braw[2][BN * ROWBYTES];   // 64 KB double buffer
    __shared__ float Trow[BM];

    const int tid = threadIdx.x;
    const int wv = tid >> 6, ln = tid & 63;
    const int sp = blockIdx.x >> 7;          // split 0..3
    const int rt = blockIdx.x & 127;         // row tile 0..127
    const int R0 = rt * BM;
    const int C0 = sp * CPS;
    const int wrow0 = R0 + wv * 32;
    const int lr = ln & 15;                  // row within strip
    const int kc = ln >> 4;                  // k-chunk 0..3

    // A fragments (row points): load once, pin in registers for both phases
    s16x8 afrag[2][16];
    float sqr[2];
    #pragma unroll
    for (int s = 0; s < 2; ++s) {
        const int row = wrow0 + s * 16 + lr;
        const unsigned long rb = (unsigned long)row * ROWBYTES;
        const int kxA = (kc << 4) ^ ((row & 7) << 4);
        #pragma unroll
        for (int t = 0; t < 16; ++t) {
            afrag[s][t] = *(const s16x8*)(obsb + rb + ((t * 64) ^ kxA));
            pinreg(afrag[s][t]);
        }
        sqr[s] = sq[row];
    }

    // LDS read bases for column frags: addr = bse[cg][t&1] + (t>>1)*128
    int bse[2][2];
    #pragma unroll
    for (int cg = 0; cg < 2; ++cg) {
        const int colL = cg * 16 + lr;
        const int s7 = (colL & 7) << 4;
        const int kxlow = (kc << 4) ^ (s7 & 0x30);
        const int b6 = (s7 >> 6) & 1;
        bse[cg][0] = colL * ROWBYTES + kxlow + (b6 << 6);
        bse[cg][1] = colL * ROWBYTES + kxlow + ((1 ^ b6) << 6);
    }

#define STAGE(BUF, CITER) do {                                                  \
        const char* gs_ = obsb + (unsigned long)(C0 + (CITER) * BN) * ROWBYTES  \
                          + wv * 1024 + ln * 16;                                \
        char* lb_ = &Braw[BUF][0] + wv * 1024;                                  \
        _Pragma("unroll")                                                       \
        for (int r_ = 0; r_ < 8; ++r_)                                          \
            gload_lds16(gs_ + r_ * 4096, lb_ + r_ * 4096);                      \
    } while (0)

#define GEMM_BODY(CUR, CITER)                                                   \
        const char* bp = &Braw[CUR][0];                                         \
        f32x4 acc[2][2] = {{{0.f,0.f,0.f,0.f},{0.f,0.f,0.f,0.f}},               \
                           {{0.f,0.f,0.f,0.f},{0.f,0.f,0.f,0.f}}};              \
        _Pragma("unroll")                                                       \
        for (int cg = 0; cg < 2; ++cg) {                                        \
            _Pragma("unroll")                                                   \
            for (int t = 0; t < 16; ++t) {                                      \
                const s16x8 b = *(const s16x8*)(bp + bse[cg][t & 1] + (t >> 1) * 128); \
                acc[0][cg] = __builtin_amdgcn_mfma_f32_16x16x32_bf16(b, afrag[0][t], acc[0][cg], 0, 0, 0); \
                acc[1][cg] = __builtin_amdgcn_mfma_f32_16x16x32_bf16(b, afrag[1][t], acc[1][cg], 0, 0, 0); \
            }                                                                   \
        }                                                                       \
        f32x4 sqv[2];                                                           \
        sqv[0] = *(const f32x4*)(sq + C0 + (CITER) * BN + kc * 4);              \
        sqv[1] = *(const f32x4*)(sq + C0 + (CITER) * BN + 16 + kc * 4);

#define DIST(S, CG, R) fmaf(-2.0f, acc[S][CG][R], sqr[S] + sqv[CG][R])

    // ================= phase A: slot minima over sampled 2048 cols =================
    float segmin[2][8];
    #pragma unroll
    for (int s = 0; s < 2; ++s)
        #pragma unroll
        for (int q = 0; q < 8; ++q) segmin[s][q] = __builtin_inff();

    STAGE(0, 0);
    __syncthreads();
    #pragma unroll 2
    for (int it = 0; it < SAMPLE_ITERS; ++it) {
        const int cur = it & 1;
        if (it + 1 < SAMPLE_ITERS) STAGE(cur ^ 1, it + 1);
        GEMM_BODY(cur, it);
        #pragma unroll
        for (int s = 0; s < 2; ++s)
            #pragma unroll
            for (int cg = 0; cg < 2; ++cg)
                #pragma unroll
                for (int r = 0; r < 4; ++r)
                    segmin[s][cg * 4 + r] = fminf(segmin[s][cg * 4 + r], DIST(s, cg, r));
        __syncthreads();
    }

    // gather 32 slot-minima per row (stride 33 to avoid bank conflicts) -> T
    float* mins = (float*)&Braw[0][0];               // [BM][33]
    #pragma unroll
    for (int s = 0; s < 2; ++s)
        #pragma unroll
        for (int q = 0; q < 8; ++q)
            mins[(wv * 32 + s * 16 + lr) * 33 + kc * 8 + q] = segmin[s][q];
    __syncthreads();
    if (tid < BM) {
        float a[KSEL];
        Trow[tid] = topk_scan(mins + tid * 33, 32, a);
    }
    __syncthreads();

    // ================= phase B: seeded per-lane register heaps =================
    float hp[2][KSEL], hmax[2], mxv[2], tseed[2];
    #pragma unroll
    for (int s = 0; s < 2; ++s) {
        #pragma unroll
        for (int p = 0; p < KSEL; ++p) hp[s][p] = __builtin_inff();
        hmax[s]  = __builtin_inff();
        tseed[s] = Trow[wv * 32 + s * 16 + lr] + 1e-3f;
        mxv[s]   = tseed[s];
    }
    __syncthreads();   // Trow read before Braw[0] re-staged below

#define INS(S, VV) do {                                                         \
        if (__any((VV) < mxv[S])) {                                             \
            const bool ins_ = (VV) < mxv[S];                                    \
            bool done_ = !ins_;                                                 \
            _Pragma("unroll")                                                   \
            for (int p = 0; p < KSEL; ++p) {                                    \
                const bool rep_ = (!done_) && (hp[S][p] == hmax[S]);            \
                hp[S][p] = rep_ ? (VV) : hp[S][p];                              \
                done_ = done_ || rep_;                                          \
            }                                                                   \
            float m_ = hp[S][0];                                                \
            _Pragma("unroll")                                                   \
            for (int p = 1; p < KSEL; ++p) m_ = fmaxf(m_, hp[S][p]);            \
            hmax[S] = m_;                                                       \
            mxv[S]  = fminf(tseed[S], m_);                                      \
        }                                                                       \
    } while (0)

#define PHASEB_STRIP(S) do {                                                    \
        const float w0 = DIST(S,0,0), w1 = DIST(S,0,1), w2 = DIST(S,0,2), w3 = DIST(S,0,3); \
        const float w4 = DIST(S,1,0), w5 = DIST(S,1,1), w6 = DIST(S,1,2), w7 = DIST(S,1,3); \
        INS(S,w0); INS(S,w1); INS(S,w2); INS(S,w3);                             \
        INS(S,w4); INS(S,w5); INS(S,w6); INS(S,w7);                             \
    } while (0)

    STAGE(0, 0);
    __syncthreads();
    #pragma unroll 2
    for (int it = 0; it < ITERS; ++it) {
        const int cur = it & 1;
        if (it + 1 < ITERS) STAGE(cur ^ 1, it + 1);
        GEMM_BODY(cur, it);
        PHASEB_STRIP(0);
        PHASEB_STRIP(1);
        __syncthreads();
    }

    // merge 4 lanes x 11 per row -> exact top-11 of this split (stride 45, pad)
    float* sc2 = (float*)&Braw[0][0];                // [BM][45]
    #pragma unroll
    for (int s = 0; s < 2; ++s)
        #pragma unroll
        for (int p = 0; p < KSEL; ++p)
            sc2[(wv * 32 + s * 16 + lr) * 45 + kc * KSEL + p] = hp[s][p];
    __syncthreads();
    if (tid < BM) {
        float a[KSEL];
        topk_scan(sc2 + tid * 45, 44, a);
        #pragma unroll
        for (int p = 0; p < KSEL; ++p)
            cand[(unsigned long)(R0 + tid) * (NSPLIT * KSEL) + sp * KSEL + p] = a[p];
    }
}

// ---- kernel 4: merge 4x11 split candidates per row -> output
__global__ void merge_out(const float* __restrict__ cand, float* __restrict__ out) {
    const int row = blockIdx.x * 256 + threadIdx.x;
    const float* c = cand + (unsigned long)row * (NSPLIT * KSEL);
    float arr[KSEL];
    topk_scan(c, NSPLIT * KSEL, arr);
    float mn = arr[0];
    #pragma unroll
    for (int q = 1; q < KSEL; ++q) mn = fminf(mn, arr[q]);
    float ssum = 0.f;
    #pragma unroll
    for (int q = 0; q < KSEL; ++q) ssum += sqrtf(fmaxf(arr[q], 0.f));
    out[row] = log1pf((ssum - sqrtf(fmaxf(mn, 0.f))) * 0.1f);
}

extern "C" void kernel_launch(void* const* d_in, const int* in_sizes, int n_in,
                              void* d_out, int out_size, void* d_ws, size_t ws_size,
                              hipStream_t stream) {
    const float* obs = (const float*)d_in[0];
    float* out = (float*)d_out;
    char* ws = (char*)d_ws;

    char*  obsb = ws;                                        // 16 MB swizzled bf16
    float* sq   = (float*)(ws + (size_t)NPTS * ROWBYTES);    // 64 KB
    float* cand = (float*)(ws + (size_t)NPTS * ROWBYTES + NPTS * sizeof(float)); // ~2.9 MB

    prep_convert<<<NPTS * 64 / 256, 256, 0, stream>>>(obs, obsb);
    prep_sq<<<NPTS / 4, 256, 0, stream>>>(obs, sq);
    knn_main<<<(NPTS / BM) * NSPLIT, 256, 0, stream>>>(obsb, sq, cand);  // 512 blocks
    merge_out<<<NPTS / 256, 256, 0, stream>>>(cand, out);
}